// Round 4
// baseline (27494.461 us; speedup 1.0000x reference)
//
#include <hip/hip_runtime.h>
#include <math.h>

// TD3ActorDSNN — f32 arithmetic-class-faithful implementation.
// Theory: ref=np computes in f32 (BLAS fma chains, k-ascending). Spike
// nonlinearity amplifies any out-of-class GEMM rounding into flips.
// So: h0 = fma chain; h1 = conditional adds (bit-exact == fma chain with
// 0/1 A-operand); recurrences = mul-then-add via __f*_rn; h2/mem2 order-free.

typedef unsigned int u32;
typedef unsigned long long u64;
typedef unsigned char u8;

// ---- K1: h0 = inputs @ W0 (f32 fma chain, k ascending, 1 acc/element) ----
// block: 256 threads = 256 cols; 32 rows per block. grid (8, 128).
__global__ __launch_bounds__(256) void h0_kernel(
    const float* __restrict__ in, const float* __restrict__ W0,
    float* __restrict__ h0) {
    __shared__ float Ls[32 * 512];
    int tid = threadIdx.x;
    int j = blockIdx.x * 256 + tid;
    int r0 = blockIdx.y * 32;
#pragma unroll
    for (int i = 0; i < 64; ++i) {
        int e = i * 256 + tid;
        Ls[e] = in[(size_t)(r0 + (e >> 9)) * 512 + (e & 511)];
    }
    __syncthreads();
    float acc[32];
#pragma unroll
    for (int r = 0; r < 32; ++r) acc[r] = 0.f;
    for (int k = 0; k < 512; ++k) {
        float w = W0[(size_t)k * 2048 + j];
#pragma unroll
        for (int r = 0; r < 32; ++r)
            acc[r] = __fmaf_rn(Ls[r * 512 + k], w, acc[r]);
    }
#pragma unroll
    for (int r = 0; r < 32; ++r)
        h0[(size_t)(r0 + r) * 2048 + j] = acc[r];
}

// ---- K2: mem0 recurrence (np order) -> transposed bit-masks bmt[t][k][row/32] ----
// block: 32 rows x 8 neurons = 256 thr. grid (256, 128).
__global__ __launch_bounds__(256) void rec0_kernel(
    const float* __restrict__ h0, u32* __restrict__ bmt) {
    int tid = threadIdx.x;
    int r = tid & 31, nn = tid >> 5;
    int rb = blockIdx.y;
    int n = blockIdx.x * 8 + nn;
    int row = rb * 32 + r;
    float h = h0[(size_t)row * 2048 + n];
    float mem = 0.f;
    u32 bits = 0;
#pragma unroll
    for (int t = 0; t < 15; ++t) {
        float nm = __fadd_rn(__fmul_rn(0.85f, mem), h);  // np: mul, then add
        bool sp = nm > 1.0f;                             // == (nm-1>0), Sterbenz
        bits |= (sp ? 1u : 0u) << t;
        mem = sp ? 0.f : nm;
    }
#pragma unroll
    for (int t = 0; t < 15; ++t) {
        u64 mask = __ballot((bits >> t) & 1u);
        // wave = lanes 0..63: lanes 0..31 -> nn even, 32..63 -> nn odd
        if (r == 0)
            bmt[((size_t)t * 2048 + n) * 128 + rb] = (u32)(mask >> ((nn & 1) * 32));
    }
}

// ---- K3: h1 = s0 @ W1 via k-ascending conditional adds (bit-exact fma chain);
//          syn1/mem1 update in np order; s1 bytes. ----
// block: 64 cols x 4 row-quarters = 256 thr; covers 64 cols x 128 rows.
// grid (32, 32). Hot kernel: 15 launches.
__global__ __launch_bounds__(256) void h1_step(
    const float* __restrict__ W1, const u32* __restrict__ bmt_t,
    float* __restrict__ syn1, float* __restrict__ mem1,
    u8* __restrict__ s1, int first) {
    int tid = threadIdx.x;
    int j = blockIdx.x * 64 + (tid & 63);
    int q = tid >> 6;
    int r0 = blockIdx.y * 128 + q * 32;
    int rw = r0 >> 5;   // uniform per wave
    float acc[32];
#pragma unroll
    for (int r = 0; r < 32; ++r) acc[r] = 0.f;
    for (int k = 0; k < 2048; ++k) {
        float w = W1[(size_t)k * 2048 + j];
        u32 m = bmt_t[(size_t)k * 128 + rw];
#pragma unroll
        for (int r = 0; r < 32; ++r)
            acc[r] = __fadd_rn(acc[r], ((m >> r) & 1u) ? w : 0.0f);
    }
#pragma unroll
    for (int r = 0; r < 32; ++r) {
        size_t idx = (size_t)(r0 + r) * 2048 + j;
        float h1 = acc[r];
        float ns, nm;
        if (first) { ns = h1; nm = ns; }           // 0.9*0+h1 == h1 exactly
        else {
            ns = __fadd_rn(__fmul_rn(0.9f, syn1[idx]), h1);
            nm = __fadd_rn(__fmul_rn(0.85f, mem1[idx]), ns);
        }
        bool sp = nm > 1.0f;
        syn1[idx] = ns;
        mem1[idx] = sp ? 0.f : nm;
        s1[idx] = sp ? (u8)1 : (u8)0;
    }
}

// ---- K4: mem2 += s1 @ W2 (order-free: mem2 feeds only tanh); last: out ----
__global__ __launch_bounds__(256) void layer2_kernel(
    const u8* __restrict__ s1, const float* __restrict__ W2,
    float* __restrict__ mem2, float* __restrict__ out, int first, int last) {
    int wv = threadIdx.x >> 6, lane = threadIdx.x & 63;
    int row = blockIdx.x * 4 + wv;
    const u8* srow = s1 + (size_t)row * 2048;
    float acc[8] = {0, 0, 0, 0, 0, 0, 0, 0};
    for (int k = lane; k < 2048; k += 64) {
        if (srow[k]) {
            float4 wa = *(const float4*)(W2 + (size_t)k * 8);
            float4 wb = *(const float4*)(W2 + (size_t)k * 8 + 4);
            acc[0] = __fadd_rn(acc[0], wa.x); acc[1] = __fadd_rn(acc[1], wa.y);
            acc[2] = __fadd_rn(acc[2], wa.z); acc[3] = __fadd_rn(acc[3], wa.w);
            acc[4] = __fadd_rn(acc[4], wb.x); acc[5] = __fadd_rn(acc[5], wb.y);
            acc[6] = __fadd_rn(acc[6], wb.z); acc[7] = __fadd_rn(acc[7], wb.w);
        }
    }
#pragma unroll
    for (int jj = 0; jj < 8; ++jj) {
        float v = acc[jj];
#pragma unroll
        for (int m = 1; m < 64; m <<= 1) v += __shfl_xor(v, m, 64);
        acc[jj] = v;
    }
    if (lane == 0) {
        float* m2 = mem2 + (size_t)row * 8;
        float* o = out + (size_t)row * 8;
#pragma unroll
        for (int jj = 0; jj < 8; ++jj) {
            float nm = __fadd_rn(first ? 0.f : m2[jj], acc[jj]);
            m2[jj] = nm;
            if (last) o[jj] = tanhf(nm);
        }
    }
}

extern "C" void kernel_launch(void* const* d_in, const int* in_sizes, int n_in,
                              void* d_out, int out_size, void* d_ws, size_t ws_size,
                              hipStream_t stream) {
    const float* inp = (const float*)d_in[0];
    const float* W0  = (const float*)d_in[1];
    const float* W1  = (const float*)d_in[2];
    const float* W2  = (const float*)d_in[3];
    float* out = (float*)d_out;
    char* ws = (char*)d_ws;

    float* h0   = (float*)(ws + 0);              // 33,554,432
    u32*   bmt  = (u32*)(ws + 33554432);         // 15,728,640 (15 x 2048 x 128 u32)
    float* syn1 = (float*)(ws + 49283072);       // 33,554,432
    float* mem1 = (float*)(ws + 82837504);       // 33,554,432
    u8*    s1u8 = (u8*)(ws + 116391936);         //  8,388,608
    float* mem2 = (float*)(ws + 124780544);      //    131,072
    if (ws_size < 124911616) return;             // ~125 MB scratch

    h0_kernel<<<dim3(8, 128), 256, 0, stream>>>(inp, W0, h0);
    rec0_kernel<<<dim3(256, 128), 256, 0, stream>>>(h0, bmt);

    for (int t = 1; t <= 15; ++t) {
        h1_step<<<dim3(32, 32), 256, 0, stream>>>(
            W1, bmt + (size_t)(t - 1) * 2048 * 128,
            syn1, mem1, s1u8, t == 1 ? 1 : 0);
        layer2_kernel<<<1024, 256, 0, stream>>>(
            s1u8, W2, mem2, out, t == 1 ? 1 : 0, t == 15 ? 1 : 0);
    }
}

// Round 5
// 18009.927 us; speedup vs baseline: 1.5266x; 1.5266x over previous
//
#include <hip/hip_runtime.h>
#include <math.h>

// TD3ActorDSNN — f32 arithmetic-class-faithful, 15-step-FUSED version.
// Key invariants (validated round 4):
//  - h0: k-ascending f32 fma chain, single accumulator per element.
//  - h1_t[row][j]: k-ascending chain of conditional adds == BLAS fma chain
//    (multiplier in {0.0f,1.0f} makes fma exact). Order must not change.
//  - recurrences: __fadd_rn(__fmul_rn(beta, state), h) — np's mul-then-add.
//  - layer 2 / mem2: order-free (feeds only tanh; tolerance 2e-2 vs ~1e-6 noise).
// Fusion: s0_t depends only on h0, so all 15 h1_t chains run in ONE k-pass
// with 15 accumulators; syn1/mem1 recurrence runs in-register afterwards.

typedef unsigned int u32;
typedef unsigned short u16;
typedef unsigned long long u64;

// ---- K1: h0 = inputs @ W0 (f32 fma chain, k ascending, 1 acc/element) ----
// UNCHANGED from validated round-4 kernel. grid (8, 128), block 256.
__global__ __launch_bounds__(256) void h0_kernel(
    const float* __restrict__ in, const float* __restrict__ W0,
    float* __restrict__ h0) {
    __shared__ float Ls[32 * 512];
    int tid = threadIdx.x;
    int j = blockIdx.x * 256 + tid;
    int r0 = blockIdx.y * 32;
#pragma unroll
    for (int i = 0; i < 64; ++i) {
        int e = i * 256 + tid;
        Ls[e] = in[(size_t)(r0 + (e >> 9)) * 512 + (e & 511)];
    }
    __syncthreads();
    float acc[32];
#pragma unroll
    for (int r = 0; r < 32; ++r) acc[r] = 0.f;
    for (int k = 0; k < 512; ++k) {
        float w = W0[(size_t)k * 2048 + j];
#pragma unroll
        for (int r = 0; r < 32; ++r)
            acc[r] = __fmaf_rn(Ls[r * 512 + k], w, acc[r]);
    }
#pragma unroll
    for (int r = 0; r < 32; ++r)
        h0[(size_t)(r0 + r) * 2048 + j] = acc[r];
}

// ---- K2: mem0 recurrence (np order) -> s0bT[k][row] u16 (bits t=0..14) ----
// LDS-transposed so both the h0 read and the s0bT write are coalesced.
// grid (64 rowblocks, 32 kblocks), block 256.
__global__ __launch_bounds__(256) void rec0T(const float* __restrict__ h0,
                                             u16* __restrict__ s0bT) {
    __shared__ float T[64][65];
    int rb = blockIdx.x * 64, nb = blockIdx.y * 64;
    int tid = threadIdx.x;
#pragma unroll
    for (int i = 0; i < 16; ++i) {
        int e = i * 256 + tid;
        int r = e >> 6, n = e & 63;
        T[r][n] = h0[(size_t)(rb + r) * 2048 + nb + n];
    }
    __syncthreads();
    int row = tid & 63;
#pragma unroll
    for (int i = 0; i < 16; ++i) {
        int n = (tid >> 6) + i * 4;
        float h = T[row][n];
        float mem = 0.f;
        u32 bits = 0;
#pragma unroll
        for (int t = 0; t < 15; ++t) {
            float nm = __fadd_rn(__fmul_rn(0.85f, mem), h);  // np: mul, then add
            bool sp = nm > 1.0f;
            bits |= (sp ? 1u : 0u) << t;
            mem = sp ? 0.f : nm;
        }
        s0bT[(size_t)(nb + n) * 4096 + rb + row] = (u16)bits;
    }
}

// ---- K3: FUSED h1 for all 15 steps + in-register syn1/mem1 recurrence ----
// One k-pass: per (row, j): 15 accumulators, each the exact k-ascending
// conditional-add chain for its step. Bitmask is wave-uniform (readfirstlane)
// so the {0,1}->float select can stay scalar; fmac multiplier in {0.0,1.0}
// is exact. Epilogue: 15-step layer-1 recurrence in-register -> s1 bitmask.
// Lane = col j (64 per wave); wave = 4 rows; block = 16 rows x 64 cols.
// grid 8192 linear, XCD-chunk swizzled (same cols -> same XCD L2).
__global__ __launch_bounds__(256, 4) void h1_fused(
    const float* __restrict__ W1, const u16* __restrict__ s0bT,
    u16* __restrict__ s1b) {
    int id = blockIdx.x;
    int wg = (id & 7) * 1024 + (id >> 3);   // bijective (8192 = 8*1024)
    int cx = wg >> 8;                        // col block 0..31
    int ry = wg & 255;                       // row block 0..255
    int lane = threadIdx.x & 63, wv = threadIdx.x >> 6;
    int j = cx * 64 + lane;
    int r0 = ry * 16 + wv * 4;               // 4 rows per wave

    float acc[4][15];
#pragma unroll
    for (int r = 0; r < 4; ++r)
#pragma unroll
        for (int t = 0; t < 15; ++t) acc[r][t] = 0.f;

    const float* wcol = W1 + j;
    const u16* bp = s0bT + r0;               // + k*4096 per k

#pragma unroll 2
    for (int k = 0; k < 2048; ++k) {
        float w = wcol[(size_t)k * 2048];
        // 4 rows' 15-bit masks: contiguous u16x4 = 8B, same addr in all lanes
        uint2 bw = *(const uint2*)(bp + (size_t)k * 4096);
        u32 lo = __builtin_amdgcn_readfirstlane(bw.x);
        u32 hi = __builtin_amdgcn_readfirstlane(bw.y);
#pragma unroll
        for (int r = 0; r < 4; ++r) {
            u32 word = (r < 2) ? lo : hi;
            u32 bits = (word >> ((r & 1) * 16)) & 0x7FFFu;
#pragma unroll
            for (int t = 0; t < 15; ++t) {
                float b = ((bits >> t) & 1u) ? 1.0f : 0.0f;  // uniform select
                acc[r][t] = __fmaf_rn(b, w, acc[r][t]);      // exact: b in {0,1}
            }
        }
    }

    // layer-1 recurrence per element, np rounding order; emit s1 bits
#pragma unroll
    for (int r = 0; r < 4; ++r) {
        float syn = 0.f, mem = 0.f;
        u32 obits = 0;
#pragma unroll
        for (int t = 0; t < 15; ++t) {
            float ns = __fadd_rn(__fmul_rn(0.9f, syn), acc[r][t]);
            float nm = __fadd_rn(__fmul_rn(0.85f, mem), ns);
            bool sp = nm > 1.0f;
            obits |= (sp ? 1u : 0u) << t;
            syn = ns;
            mem = sp ? 0.f : nm;
        }
        s1b[(size_t)(r0 + r) * 2048 + j] = (u16)obits;
    }
}

// ---- K4: out = tanh(sum_t s1_t @ W2), all 15 t in one kernel ----
// mem2 only feeds tanh -> reduction order free. Block per row; thread owns
// 8 consecutive k; per t: conditional adds + wave reduce; cross-wave via LDS;
// t-chain summed in ascending order.
__global__ __launch_bounds__(256) void out_kernel(
    const u16* __restrict__ s1b, const float* __restrict__ W2,
    float* __restrict__ out) {
    __shared__ float P[4][15][8];
    int row = blockIdx.x;
    int tid = threadIdx.x, lane = tid & 63, wv = tid >> 6;
    const u16* srow = s1b + (size_t)row * 2048;
    union { uint4 v; u16 m[8]; } u;
    u.v = *(const uint4*)(srow + tid * 8);
#pragma unroll
    for (int t = 0; t < 15; ++t) {
        float a[8];
#pragma unroll
        for (int jj = 0; jj < 8; ++jj) a[jj] = 0.f;
#pragma unroll
        for (int kk = 0; kk < 8; ++kk) {
            const float* wr = W2 + (size_t)(tid * 8 + kk) * 8;
            if ((u.m[kk] >> t) & 1u) {
#pragma unroll
                for (int jj = 0; jj < 8; ++jj)
                    a[jj] = __fadd_rn(a[jj], wr[jj]);
            }
        }
#pragma unroll
        for (int jj = 0; jj < 8; ++jj) {
            float v = a[jj];
#pragma unroll
            for (int m = 1; m < 64; m <<= 1) v += __shfl_xor(v, m, 64);
            a[jj] = v;
        }
        if (lane == 0) {
#pragma unroll
            for (int jj = 0; jj < 8; ++jj) P[wv][t][jj] = a[jj];
        }
    }
    __syncthreads();
    if (tid < 8) {
        float m2 = 0.f;
#pragma unroll
        for (int t = 0; t < 15; ++t) {
            float s = __fadd_rn(__fadd_rn(P[0][t][tid], P[1][t][tid]),
                                __fadd_rn(P[2][t][tid], P[3][t][tid]));
            m2 = __fadd_rn(m2, s);
        }
        out[(size_t)row * 8 + tid] = tanhf(m2);
    }
}

extern "C" void kernel_launch(void* const* d_in, const int* in_sizes, int n_in,
                              void* d_out, int out_size, void* d_ws, size_t ws_size,
                              hipStream_t stream) {
    const float* inp = (const float*)d_in[0];
    const float* W0  = (const float*)d_in[1];
    const float* W1  = (const float*)d_in[2];
    const float* W2  = (const float*)d_in[3];
    float* out = (float*)d_out;
    char* ws = (char*)d_ws;

    float* h0   = (float*)(ws + 0);          // 33,554,432
    u16*   s0bT = (u16*)(ws + 33554432);     // 16,777,216  [k][row] bitmasks
    u16*   s1b  = (u16*)(ws + 50331648);     // 16,777,216  [row][j] bitmasks
    if (ws_size < 67108864) return;          // 64 MB scratch

    h0_kernel<<<dim3(8, 128), 256, 0, stream>>>(inp, W0, h0);
    rec0T<<<dim3(64, 32), 256, 0, stream>>>(h0, s0bT);
    h1_fused<<<8192, 256, 0, stream>>>(W1, s0bT, s1b);
    out_kernel<<<4096, 256, 0, stream>>>(s1b, W2, out);
}

// Round 6
// 4193.528 us; speedup vs baseline: 6.5564x; 4.2947x over previous
//
#include <hip/hip_runtime.h>
#include <math.h>

// TD3ActorDSNN — f32 class-faithful, fused, round 6.
// Exactness invariants (validated r4/r5):
//  - per-element k-ascending single-accumulator f32 chains for h0 and h1;
//    conditional-add == fmaf with b in {0,1} (exact); skipping b==0 terms
//    is bit-identical (fmaf(0,w,acc)==acc).
//  - recurrences: __fadd_rn(__fmul_rn(beta,state),h) (np mul-then-add).
//  - layer2/mem2: order-free (tanh input, tol 2e-2 >> 1e-6 noise).
// Round-6 changes (all bit-identical math, pure restructure):
//  - rec0 fused into h0 epilogue -> s0bR[row][k] u16 masks (no h0 array).
//  - h1: 1 row x 256 cols per wave (amortize bit-builds over 4x cols),
//    zero-mask uniform skip (~56% of k), uint4 mask prefetch (8 k/load),
//    1-ahead w float4 prefetch. XCD-affine jb = blockIdx&7 (W1 slice/XCD L2).

typedef unsigned int u32;
typedef unsigned short u16;

// ---- K1: h0 = inputs @ W0 (f32 fma chain) + fused mem0 recurrence -> s0bR ----
// grid (8, 128), block 256. j = bx*256+tid, rows by*32.. (32 per block).
__global__ __launch_bounds__(256) void h0_kernel(
    const float* __restrict__ in, const float* __restrict__ W0,
    u16* __restrict__ s0bR) {
    __shared__ float Ls[32 * 512];
    int tid = threadIdx.x;
    int j = blockIdx.x * 256 + tid;
    int r0 = blockIdx.y * 32;
#pragma unroll
    for (int i = 0; i < 64; ++i) {
        int e = i * 256 + tid;
        Ls[e] = in[(size_t)(r0 + (e >> 9)) * 512 + (e & 511)];
    }
    __syncthreads();
    float acc[32];
#pragma unroll
    for (int r = 0; r < 32; ++r) acc[r] = 0.f;
    for (int k = 0; k < 512; ++k) {
        float w = W0[(size_t)k * 2048 + j];
#pragma unroll
        for (int r = 0; r < 32; ++r)
            acc[r] = __fmaf_rn(Ls[r * 512 + k], w, acc[r]);
    }
#pragma unroll
    for (int r = 0; r < 32; ++r) {
        float h = acc[r], mem = 0.f;
        u32 bits = 0;
#pragma unroll
        for (int t = 0; t < 15; ++t) {
            float nm = __fadd_rn(__fmul_rn(0.85f, mem), h);  // np: mul, then add
            bool sp = nm > 1.0f;
            bits |= (sp ? 1u : 0u) << t;
            mem = sp ? 0.f : nm;
        }
        s0bR[(size_t)(r0 + r) * 2048 + j] = (u16)bits;
    }
}

// ---- K2: FUSED h1 (15 steps) + in-register syn1/mem1 recurrence -> s1b ----
// Wave: 1 row x 256 cols (lane holds j0..j0+3 via float4). Block: 4 rows,
// same jb. grid 8192: jb = id&7 (XCD-affine), rowblk = id>>3.
__global__ __launch_bounds__(256, 4) void h1_fused2(
    const float* __restrict__ W1, const u16* __restrict__ s0bR,
    u16* __restrict__ s1b) {
    int id = blockIdx.x;
    int jb = id & 7, rblk = id >> 3;
    int lane = threadIdx.x & 63, wv = threadIdx.x >> 6;
    int row = rblk * 4 + wv;
    int j0 = jb * 256 + lane * 4;
    const float* wp = W1 + j0;
    const u16* mp = s0bR + (size_t)row * 2048;

    float acc[15][4];
#pragma unroll
    for (int t = 0; t < 15; ++t)
#pragma unroll
        for (int q = 0; q < 4; ++q) acc[t][q] = 0.f;

    float4 wc = *(const float4*)(wp);       // w for k=0
    uint4 m8 = *(const uint4*)(mp);         // masks k=0..7
    for (int kb = 0; kb < 2048; kb += 8) {
        // lookahead masks (last read overruns row into next row / s1b: unused)
        uint4 m8n = *(const uint4*)(mp + kb + 8);
#pragma unroll
        for (int kk = 0; kk < 8; ++kk) {
            int k = kb + kk;
            float4 wcur = wc;
            // prefetch next k's w (guard last k; uniform select)
            wc = *(const float4*)(wp + (size_t)(k < 2047 ? k + 1 : k) * 2048);
            u32 word = (kk < 2) ? m8.x : (kk < 4) ? m8.y : (kk < 6) ? m8.z : m8.w;
            u32 mask = (kk & 1) ? (word >> 16) : (word & 0xFFFFu);
            if (mask) {                      // wave-uniform branch (~44% taken)
#pragma unroll
                for (int t = 0; t < 15; ++t) {
                    float b = (float)((mask >> t) & 1u);   // v_bfe + v_cvt
                    acc[t][0] = __fmaf_rn(b, wcur.x, acc[t][0]);  // exact
                    acc[t][1] = __fmaf_rn(b, wcur.y, acc[t][1]);
                    acc[t][2] = __fmaf_rn(b, wcur.z, acc[t][2]);
                    acc[t][3] = __fmaf_rn(b, wcur.w, acc[t][3]);
                }
            }
        }
        m8 = m8n;
    }

    // layer-1 recurrence per element (np rounding order) -> s1 bitmasks
    u16 ob[4];
#pragma unroll
    for (int q = 0; q < 4; ++q) {
        float syn = 0.f, mem = 0.f;
        u32 obits = 0;
#pragma unroll
        for (int t = 0; t < 15; ++t) {
            float ns = __fadd_rn(__fmul_rn(0.9f, syn), acc[t][q]);
            float nm = __fadd_rn(__fmul_rn(0.85f, mem), ns);
            bool sp = nm > 1.0f;
            obits |= (sp ? 1u : 0u) << t;
            syn = ns;
            mem = sp ? 0.f : nm;
        }
        ob[q] = (u16)obits;
    }
    uint2 pk;
    pk.x = (u32)ob[0] | ((u32)ob[1] << 16);
    pk.y = (u32)ob[2] | ((u32)ob[3] << 16);
    *(uint2*)(s1b + (size_t)row * 2048 + j0) = pk;
}

// ---- K3: out = tanh(sum_t s1_t @ W2) (order-free reduction) ----
__global__ __launch_bounds__(256) void out_kernel(
    const u16* __restrict__ s1b, const float* __restrict__ W2,
    float* __restrict__ out) {
    __shared__ float P[4][15][8];
    int row = blockIdx.x;
    int tid = threadIdx.x, lane = tid & 63, wv = tid >> 6;
    const u16* srow = s1b + (size_t)row * 2048;
    union { uint4 v; u16 m[8]; } u;
    u.v = *(const uint4*)(srow + tid * 8);
#pragma unroll
    for (int t = 0; t < 15; ++t) {
        float a[8];
#pragma unroll
        for (int jj = 0; jj < 8; ++jj) a[jj] = 0.f;
#pragma unroll
        for (int kk = 0; kk < 8; ++kk) {
            const float* wr = W2 + (size_t)(tid * 8 + kk) * 8;
            if ((u.m[kk] >> t) & 1u) {
#pragma unroll
                for (int jj = 0; jj < 8; ++jj)
                    a[jj] = __fadd_rn(a[jj], wr[jj]);
            }
        }
#pragma unroll
        for (int jj = 0; jj < 8; ++jj) {
            float v = a[jj];
#pragma unroll
            for (int m = 1; m < 64; m <<= 1) v += __shfl_xor(v, m, 64);
            a[jj] = v;
        }
        if (lane == 0) {
#pragma unroll
            for (int jj = 0; jj < 8; ++jj) P[wv][t][jj] = a[jj];
        }
    }
    __syncthreads();
    if (tid < 8) {
        float m2 = 0.f;
#pragma unroll
        for (int t = 0; t < 15; ++t) {
            float s = __fadd_rn(__fadd_rn(P[0][t][tid], P[1][t][tid]),
                                __fadd_rn(P[2][t][tid], P[3][t][tid]));
            m2 = __fadd_rn(m2, s);
        }
        out[(size_t)row * 8 + tid] = tanhf(m2);
    }
}

extern "C" void kernel_launch(void* const* d_in, const int* in_sizes, int n_in,
                              void* d_out, int out_size, void* d_ws, size_t ws_size,
                              hipStream_t stream) {
    const float* inp = (const float*)d_in[0];
    const float* W0  = (const float*)d_in[1];
    const float* W1  = (const float*)d_in[2];
    const float* W2  = (const float*)d_in[3];
    float* out = (float*)d_out;
    char* ws = (char*)d_ws;

    u16* s0bR = (u16*)(ws + 0);           // 16,777,216  [row][k] 15-bit masks
    u16* s1b  = (u16*)(ws + 16777216);    // 16,777,216  [row][j] 15-bit masks
    if (ws_size < 33554432) return;       // 32 MB scratch

    h0_kernel<<<dim3(8, 128), 256, 0, stream>>>(inp, W0, s0bR);
    h1_fused2<<<8192, 256, 0, stream>>>(W1, s0bR, s1b);
    out_kernel<<<4096, 256, 0, stream>>>(s1b, W2, out);
}